// Round 1
// baseline (329.281 us; speedup 1.0000x reference)
//
#include <hip/hip_runtime.h>
#include <cmath>

#define LATENTS 64
#define HID 64
#define IN_DIM 65
#define SLOPE 0.2f
#define FEPS 1e-8f
#define BT 64     // batch rows per block
#define STR 67    // float2 stride per row in LDS (odd -> low bank conflict)

__global__ void lad_init_kernel(float* __restrict__ lad, int n) {
    int i = blockIdx.x * blockDim.x + threadIdx.x;
    if (i < n) lad[i] = 0.0f;
}

// One layer: reads (h,t) float2 rows from buf, writes activated outputs in place.
// Each thread: row r (= lane), 16 output cols starting at cb (wave-uniform).
template <int K, bool WVEC>
__device__ __forceinline__ void dense_layer(const float* __restrict__ Wl,
                                            const float* __restrict__ bl,
                                            float* buf, int r, int cb)
{
    float2 acc[16];
#pragma unroll
    for (int c = 0; c < 16; ++c) acc[c] = make_float2(bl[cb + c], 0.0f);

    constexpr int K4 = K / 4;
    for (int k4 = 0; k4 < K4; ++k4) {
        const float2 a0 = *(const float2*)&buf[(r * STR + 4 * k4 + 0) * 2];
        const float2 a1 = *(const float2*)&buf[(r * STR + 4 * k4 + 1) * 2];
        const float2 a2 = *(const float2*)&buf[(r * STR + 4 * k4 + 2) * 2];
        const float2 a3 = *(const float2*)&buf[(r * STR + 4 * k4 + 3) * 2];
#pragma unroll
        for (int c = 0; c < 16; ++c) {
            float w0, w1, w2, w3;
            if (WVEC) {
                const float4 w = *(const float4*)(Wl + (cb + c) * K + 4 * k4);
                w0 = w.x; w1 = w.y; w2 = w.z; w3 = w.w;
            } else {
                const float* wr = Wl + (cb + c) * K + 4 * k4;
                w0 = wr[0]; w1 = wr[1]; w2 = wr[2]; w3 = wr[3];
            }
            acc[c].x += w0 * a0.x + w1 * a1.x + w2 * a2.x + w3 * a3.x;
            acc[c].y += w0 * a0.y + w1 * a1.y + w2 * a2.y + w3 * a3.y;
        }
    }
    if (K % 4) {  // tail (K=65): single extra k = K-1
        const float2 a = *(const float2*)&buf[(r * STR + (K - 1)) * 2];
#pragma unroll
        for (int c = 0; c < 16; ++c) {
            const float w = Wl[(cb + c) * K + (K - 1)];
            acc[c].x += w * a.x;
            acc[c].y += w * a.y;
        }
    }
    __syncthreads();  // all reads of old activations complete
#pragma unroll
    for (int c = 0; c < 16; ++c) {
        const float m = (acc[c].x >= 0.0f) ? 1.0f : SLOPE;
        buf[(r * STR + cb + c) * 2 + 0] = m * acc[c].x;  // leaky_relu(z)
        buf[(r * STR + cb + c) * 2 + 1] = m * acc[c].y;  // mask * tangent
    }
    __syncthreads();
}

__global__ __launch_bounds__(256)
void flow_kernel(const float* __restrict__ x,
                 const float* __restrict__ W0, const float* __restrict__ b0,
                 const float* __restrict__ W1, const float* __restrict__ b1,
                 const float* __restrict__ W2, const float* __restrict__ b2,
                 const float* __restrict__ W3, const float* __restrict__ b3,
                 float* __restrict__ out_res, float* __restrict__ out_lad)
{
    __shared__ float buf[BT * STR * 2];  // (h, t) per (row, k)
    const int l    = blockIdx.y;
    const int row0 = blockIdx.x * BT;
    const int tid  = threadIdx.x;

    // Stage x into LDS; tangent plane = delta on last input column, so the
    // generic layer-0 tangent matvec produces W0[:, -1] exactly like the JVP.
    for (int idx = tid; idx < BT * IN_DIM; idx += 256) {
        const int r = idx / IN_DIM;
        const int k = idx - r * IN_DIM;
        const float v = x[(size_t)(row0 + r) * (LATENTS * IN_DIM) + l * IN_DIM + k];
        buf[(r * STR + k) * 2 + 0] = v;
        buf[(r * STR + k) * 2 + 1] = (k == IN_DIM - 1) ? 1.0f : 0.0f;
    }
    __syncthreads();

    const int r  = tid & 63;
    const int cb = __builtin_amdgcn_readfirstlane((tid >> 6) * 16);

    // Layer 0: K=65, rows are 260B apart -> unaligned, use scalar weight loads.
    dense_layer<IN_DIM, false>(W0 + (size_t)l * (HID * IN_DIM), b0 + l * HID, buf, r, cb);
    // Layers 1,2: K=64, 16B-aligned rows -> s_load_dwordx4 weight loads.
    dense_layer<HID, true>(W1 + (size_t)l * (HID * HID), b1 + l * HID, buf, r, cb);
    dense_layer<HID, true>(W2 + (size_t)l * (HID * HID), b2 + l * HID, buf, r, cb);

    // Final linear layer to scalar + log|dJ| accumulation.
    if (tid < BT) {
        const float* w3 = W3 + l * HID;
        float so = b3[l];
        float sd = 0.0f;
        for (int k = 0; k < HID; ++k) {
            const float w  = w3[k];  // k wave-uniform -> scalar load
            const float2 a = *(const float2*)&buf[(tid * STR + k) * 2];
            so += w * a.x;
            sd += w * a.y;
        }
        out_res[(size_t)(row0 + tid) * LATENTS + l] = so;
        const float lt = logf(fabsf(sd) + FEPS);
        atomicAdd(&out_lad[row0 + tid], lt);
    }
}

extern "C" void kernel_launch(void* const* d_in, const int* in_sizes, int n_in,
                              void* d_out, int out_size, void* d_ws, size_t ws_size,
                              hipStream_t stream)
{
    const float* x  = (const float*)d_in[0];
    const float* W0 = (const float*)d_in[1];
    const float* b0 = (const float*)d_in[2];
    const float* W1 = (const float*)d_in[3];
    const float* b1 = (const float*)d_in[4];
    const float* W2 = (const float*)d_in[5];
    const float* b2 = (const float*)d_in[6];
    const float* W3 = (const float*)d_in[7];
    const float* b3 = (const float*)d_in[8];

    const int B = in_sizes[0] / (LATENTS * IN_DIM);  // 8192
    float* out_res = (float*)d_out;
    float* out_lad = out_res + (size_t)B * LATENTS;

    lad_init_kernel<<<dim3((B + 255) / 256), dim3(256), 0, stream>>>(out_lad, B);
    flow_kernel<<<dim3(B / BT, LATENTS), dim3(256), 0, stream>>>(
        x, W0, b0, W1, b1, W2, b2, W3, b3, out_res, out_lad);
}

// Round 2
// 201.257 us; speedup vs baseline: 1.6361x; 1.6361x over previous
//
#include <hip/hip_runtime.h>
#include <hip/hip_bf16.h>
#include <cmath>

#define LATENTS 64
#define HID 64
#define IN_DIM 65
#define SLOPE 0.2f
#define FEPS 1e-8f
#define MB 64   // batch rows per block (16 per wave)

typedef __attribute__((ext_vector_type(8))) short short8;
typedef __attribute__((ext_vector_type(4))) float f32x4;

__device__ __forceinline__ unsigned asu(float f){ return __builtin_bit_cast(unsigned, f); }
__device__ __forceinline__ float    asf(unsigned u){ return __builtin_bit_cast(float, u); }

// pack fp32 -> (hi bf16 in top16 | lo bf16 in low16); hi = truncate, lo = RTNE remainder
__device__ __forceinline__ unsigned packf(float f){
    unsigned hb = asu(f) & 0xFFFF0000u;
    float lo = f - asf(hb);
    unsigned lb = (unsigned)__builtin_bit_cast(unsigned short, __float2bfloat16(lo));
    return hb | lb;
}
__device__ __forceinline__ float upackf(unsigned p){
    return asf(p & 0xFFFF0000u) + asf(p << 16);
}

// swizzled LDS address for packed-u32 [64 rows][64 cols] tiles
__device__ __forceinline__ unsigned* swp(unsigned* base, int r, int c){
    unsigned byte = ((unsigned)(r * 64 + c) << 2) ^ (((unsigned)(r >> 1) & 7u) << 4);
    return (unsigned*)((char*)base + byte);
}

// read 8 packed elems at (r, k0..k0+7) -> hi/lo bf16x8 A-fragments
__device__ __forceinline__ void read_frag(const unsigned* lds, int r, int k0,
                                          short8& hi, short8& lo){
    unsigned swz = (((unsigned)(r >> 1) & 7u) << 4);
    const char* cb = (const char*)lds;
    uint4 a = *(const uint4*)(cb + ((((unsigned)(r * 64 + k0)) << 2) ^ swz));
    uint4 b = *(const uint4*)(cb + ((((unsigned)(r * 64 + k0 + 4)) << 2) ^ swz));
    unsigned hw0 = __builtin_amdgcn_perm(a.y, a.x, 0x07060302u);
    unsigned lw0 = __builtin_amdgcn_perm(a.y, a.x, 0x05040100u);
    unsigned hw1 = __builtin_amdgcn_perm(a.w, a.z, 0x07060302u);
    unsigned lw1 = __builtin_amdgcn_perm(a.w, a.z, 0x05040100u);
    unsigned hw2 = __builtin_amdgcn_perm(b.y, b.x, 0x07060302u);
    unsigned lw2 = __builtin_amdgcn_perm(b.y, b.x, 0x05040100u);
    unsigned hw3 = __builtin_amdgcn_perm(b.w, b.z, 0x07060302u);
    unsigned lw3 = __builtin_amdgcn_perm(b.w, b.z, 0x05040100u);
    uint4 h4{hw0, hw1, hw2, hw3}, l4{lw0, lw1, lw2, lw3};
    hi = __builtin_bit_cast(short8, h4);
    lo = __builtin_bit_cast(short8, l4);
}

// split 8 fp32 into hi/lo bf16x8 fragments
__device__ __forceinline__ void split8(const float* f, short8& hi, short8& lo){
    unsigned hw[4], lw[4];
#pragma unroll
    for (int w = 0; w < 4; ++w){
        float a = f[2 * w], b = f[2 * w + 1];
        unsigned ha = asu(a) & 0xFFFF0000u, hb = asu(b) & 0xFFFF0000u;
        float la = a - asf(ha), lb = b - asf(hb);
        unsigned ua = (unsigned)__builtin_bit_cast(unsigned short, __float2bfloat16(la));
        unsigned ub = (unsigned)__builtin_bit_cast(unsigned short, __float2bfloat16(lb));
        hw[w] = (ha >> 16) | hb;
        lw[w] = ua | (ub << 16);
    }
    uint4 h4{hw[0], hw[1], hw[2], hw[3]}, l4{lw[0], lw[1], lw[2], lw[3]};
    hi = __builtin_bit_cast(short8, h4);
    lo = __builtin_bit_cast(short8, l4);
}

__device__ __forceinline__ f32x4 mfma_(short8 a, short8 b, f32x4 c){
    return __builtin_amdgcn_mfma_f32_16x16x32_bf16(a, b, c, 0, 0, 0);
}

__global__ void lad_init_kernel(float* __restrict__ lad, int n){
    int i = blockIdx.x * blockDim.x + threadIdx.x;
    if (i < n) lad[i] = 0.0f;
}

__global__ __launch_bounds__(256, 3)
void flow_mfma_kernel(const float* __restrict__ x,
                      const float* __restrict__ W0, const float* __restrict__ b0,
                      const float* __restrict__ W1, const float* __restrict__ b1,
                      const float* __restrict__ W2, const float* __restrict__ b2,
                      const float* __restrict__ W3, const float* __restrict__ b3,
                      float* __restrict__ out_res, float* __restrict__ out_lad)
{
    __shared__ unsigned h_lds[MB * 64];
    __shared__ unsigned t_lds[MB * 64];
    __shared__ float    x65s[MB];

    const int l    = blockIdx.y;
    const int row0 = blockIdx.x * MB;
    const int tid  = threadIdx.x;
    const int L    = tid & 63;
    const int wv   = tid >> 6;
    const int wr0  = wv * 16;          // this wave's private 16 rows

    // ---- stage x tile (wave-private rows; no barriers anywhere) ----
    {
        const int r  = wr0 + (L >> 2);
        const int kb = (L & 3) * 16;
        const float* xg = x + ((size_t)(row0 + r) * LATENTS + l) * IN_DIM;
#pragma unroll
        for (int j = 0; j < 16; ++j)
            *swp(h_lds, r, kb + j) = packf(xg[kb + j]);
        if ((L & 3) == 0) x65s[r] = xg[64];
    }

    const int lrow = wr0 + (L & 15);   // A-frag row for this lane
    const int lg   = L >> 4;           // k-group
    const int q0   = wr0 + lg * 4;     // D-tile row base
    const int lc   = L & 15;

    f32x4 hacc[4], tacc[4];

    // ---- layer 0: z0 = x @ W0^T + b0 (K=64 via MFMA + rank-1 col-65) ----
    {
        const float* W0l = W0 + (size_t)l * 64 * IN_DIM;
#pragma unroll
        for (int ct = 0; ct < 4; ++ct){
            float bv = b0[l * 64 + ct * 16 + lc];
            hacc[ct] = (f32x4){bv, bv, bv, bv};
        }
#pragma unroll
        for (int ks = 0; ks < 2; ++ks){
            short8 ah, al;
            read_frag(h_lds, lrow, ks * 32 + lg * 8, ah, al);
#pragma unroll
            for (int ct = 0; ct < 4; ++ct){
                const int c = ct * 16 + lc;
                const float* wrp = W0l + (size_t)c * IN_DIM + ks * 32 + lg * 8;
                float wf[8];
#pragma unroll
                for (int j = 0; j < 8; ++j) wf[j] = wrp[j];
                short8 wh, wl;
                split8(wf, wh, wl);
                hacc[ct] = mfma_(ah, wh, hacc[ct]);
                hacc[ct] = mfma_(al, wh, hacc[ct]);
                hacc[ct] = mfma_(ah, wl, hacc[ct]);
            }
        }
        // rank-1 update with column 64, then activation; tangent t1 = m * W0[:,64]
        float xv[4];
#pragma unroll
        for (int i = 0; i < 4; ++i) xv[i] = x65s[q0 + i];
#pragma unroll
        for (int ct = 0; ct < 4; ++ct){
            const int c = ct * 16 + lc;
            const float w65 = W0l[(size_t)c * IN_DIM + 64];
#pragma unroll
            for (int i = 0; i < 4; ++i){
                float z = hacc[ct][i] + xv[i] * w65;
                float m = (z >= 0.0f) ? 1.0f : SLOPE;
                *swp(h_lds, q0 + i, c) = packf(m * z);
                *swp(t_lds, q0 + i, c) = packf(m * w65);
            }
        }
    }

    // ---- layers 1 and 2: h,t GEMMs (split-bf16, 3 MFMAs per product) ----
    auto dense = [&](const float* __restrict__ Wl, const float* __restrict__ bl){
#pragma unroll
        for (int ct = 0; ct < 4; ++ct){
            float bv = bl[ct * 16 + lc];
            hacc[ct] = (f32x4){bv, bv, bv, bv};
            tacc[ct] = (f32x4){0.f, 0.f, 0.f, 0.f};
        }
#pragma unroll
        for (int ks = 0; ks < 2; ++ks){
            short8 ah, al, th, tl;
            read_frag(h_lds, lrow, ks * 32 + lg * 8, ah, al);
            read_frag(t_lds, lrow, ks * 32 + lg * 8, th, tl);
#pragma unroll
            for (int ct = 0; ct < 4; ++ct){
                const int c = ct * 16 + lc;
                const float4 w0v = *(const float4*)(Wl + (size_t)c * 64 + ks * 32 + lg * 8);
                const float4 w1v = *(const float4*)(Wl + (size_t)c * 64 + ks * 32 + lg * 8 + 4);
                float wf[8] = {w0v.x, w0v.y, w0v.z, w0v.w, w1v.x, w1v.y, w1v.z, w1v.w};
                short8 wh, wl;
                split8(wf, wh, wl);
                hacc[ct] = mfma_(ah, wh, hacc[ct]);
                hacc[ct] = mfma_(al, wh, hacc[ct]);
                hacc[ct] = mfma_(ah, wl, hacc[ct]);
                tacc[ct] = mfma_(th, wh, tacc[ct]);
                tacc[ct] = mfma_(tl, wh, tacc[ct]);
                tacc[ct] = mfma_(th, wl, tacc[ct]);
            }
        }
#pragma unroll
        for (int ct = 0; ct < 4; ++ct){
            const int c = ct * 16 + lc;
#pragma unroll
            for (int i = 0; i < 4; ++i){
                float z = hacc[ct][i], zt = tacc[ct][i];
                float m = (z >= 0.0f) ? 1.0f : SLOPE;
                *swp(h_lds, q0 + i, c) = packf(m * z);
                *swp(t_lds, q0 + i, c) = packf(m * zt);
            }
        }
    };
    dense(W1 + (size_t)l * 4096, b1 + l * 64);
    dense(W2 + (size_t)l * 4096, b2 + l * 64);

    // ---- layer 3: scalar head + log|dJ| (wave-local, shfl reduce) ----
    {
        const float* w3 = W3 + l * 64;
        const int r  = wr0 + (L & 15);
        const int kq = L >> 4;
        float so = 0.0f, sd = 0.0f;
#pragma unroll
        for (int j = 0; j < 16; ++j){
            const int k = kq * 16 + j;
            const float w = w3[k];
            so += w * upackf(*swp(h_lds, r, k));
            sd += w * upackf(*swp(t_lds, r, k));
        }
        so += __shfl_xor(so, 16, 64); so += __shfl_xor(so, 32, 64);
        sd += __shfl_xor(sd, 16, 64); sd += __shfl_xor(sd, 32, 64);
        if (kq == 0){
            out_res[(size_t)(row0 + r) * LATENTS + l] = so + b3[l];
            atomicAdd(&out_lad[row0 + r], logf(fabsf(sd) + FEPS));
        }
    }
}

extern "C" void kernel_launch(void* const* d_in, const int* in_sizes, int n_in,
                              void* d_out, int out_size, void* d_ws, size_t ws_size,
                              hipStream_t stream)
{
    const float* x  = (const float*)d_in[0];
    const float* W0 = (const float*)d_in[1];
    const float* b0 = (const float*)d_in[2];
    const float* W1 = (const float*)d_in[3];
    const float* b1 = (const float*)d_in[4];
    const float* W2 = (const float*)d_in[5];
    const float* b2 = (const float*)d_in[6];
    const float* W3 = (const float*)d_in[7];
    const float* b3 = (const float*)d_in[8];

    const int B = in_sizes[0] / (LATENTS * IN_DIM);  // 8192
    float* out_res = (float*)d_out;
    float* out_lad = out_res + (size_t)B * LATENTS;

    lad_init_kernel<<<dim3((B + 255) / 256), dim3(256), 0, stream>>>(out_lad, B);
    flow_mfma_kernel<<<dim3(B / MB, LATENTS), dim3(256), 0, stream>>>(
        x, W0, b0, W1, b1, W2, b2, W3, b3, out_res, out_lad);
}

// Round 3
// 111.761 us; speedup vs baseline: 2.9463x; 1.8008x over previous
//
#include <hip/hip_runtime.h>
#include <hip/hip_bf16.h>
#include <cmath>

#define LATENTS 64
#define HID 64
#define IN_DIM 65
#define SLOPE 0.2f
#define FEPS 1e-8f
#define MB 64   // batch rows per block (16 per wave)

typedef __attribute__((ext_vector_type(8))) short short8;
typedef __attribute__((ext_vector_type(4))) float f32x4;

__device__ __forceinline__ unsigned asu(float f){ return __builtin_bit_cast(unsigned, f); }
__device__ __forceinline__ float    asf(unsigned u){ return __builtin_bit_cast(float, u); }

// pack fp32 -> (hi bf16 in top16 | lo bf16 in low16); hi = truncate, lo = RTNE remainder
__device__ __forceinline__ unsigned packf(float f){
    unsigned hb = asu(f) & 0xFFFF0000u;
    float lo = f - asf(hb);
    unsigned lb = (unsigned)__builtin_bit_cast(unsigned short, __float2bfloat16(lo));
    return hb | lb;
}
__device__ __forceinline__ float upackf(unsigned p){
    return asf(p & 0xFFFF0000u) + asf(p << 16);
}

// swizzled LDS address for packed-u32 [64 rows][64 cols] tiles
// byte ^= (r&7)<<4: 8 consecutive rows -> 8 distinct 16B chunk slots (b128-conflict-free)
__device__ __forceinline__ unsigned* swp(unsigned* base, int r, int c){
    unsigned byte = ((unsigned)(r * 64 + c) << 2) ^ (((unsigned)r & 7u) << 4);
    return (unsigned*)((char*)base + byte);
}

// read 8 packed elems at (r, k0..k0+7) -> hi/lo bf16x8 A-fragments
__device__ __forceinline__ void read_frag(const unsigned* lds, int r, int k0,
                                          short8& hi, short8& lo){
    unsigned swz = (((unsigned)r & 7u) << 4);
    const char* cb = (const char*)lds;
    uint4 a = *(const uint4*)(cb + ((((unsigned)(r * 64 + k0)) << 2) ^ swz));
    uint4 b = *(const uint4*)(cb + ((((unsigned)(r * 64 + k0 + 4)) << 2) ^ swz));
    unsigned hw0 = __builtin_amdgcn_perm(a.y, a.x, 0x07060302u);
    unsigned lw0 = __builtin_amdgcn_perm(a.y, a.x, 0x05040100u);
    unsigned hw1 = __builtin_amdgcn_perm(a.w, a.z, 0x07060302u);
    unsigned lw1 = __builtin_amdgcn_perm(a.w, a.z, 0x05040100u);
    unsigned hw2 = __builtin_amdgcn_perm(b.y, b.x, 0x07060302u);
    unsigned lw2 = __builtin_amdgcn_perm(b.y, b.x, 0x05040100u);
    unsigned hw3 = __builtin_amdgcn_perm(b.w, b.z, 0x07060302u);
    unsigned lw3 = __builtin_amdgcn_perm(b.w, b.z, 0x05040100u);
    uint4 h4{hw0, hw1, hw2, hw3}, l4{lw0, lw1, lw2, lw3};
    hi = __builtin_bit_cast(short8, h4);
    lo = __builtin_bit_cast(short8, l4);
}

// split 8 fp32 into hi/lo bf16x8 fragments
__device__ __forceinline__ void split8(const float* f, short8& hi, short8& lo){
    unsigned hw[4], lw[4];
#pragma unroll
    for (int w = 0; w < 4; ++w){
        float a = f[2 * w], b = f[2 * w + 1];
        unsigned ha = asu(a) & 0xFFFF0000u, hb = asu(b) & 0xFFFF0000u;
        float la = a - asf(ha), lb = b - asf(hb);
        unsigned ua = (unsigned)__builtin_bit_cast(unsigned short, __float2bfloat16(la));
        unsigned ub = (unsigned)__builtin_bit_cast(unsigned short, __float2bfloat16(lb));
        hw[w] = (ha >> 16) | hb;
        lw[w] = ua | (ub << 16);
    }
    uint4 h4{hw[0], hw[1], hw[2], hw[3]}, l4{lw[0], lw[1], lw[2], lw[3]};
    hi = __builtin_bit_cast(short8, h4);
    lo = __builtin_bit_cast(short8, l4);
}

__device__ __forceinline__ f32x4 mfma_(short8 a, short8 b, f32x4 c){
    return __builtin_amdgcn_mfma_f32_16x16x32_bf16(a, b, c, 0, 0, 0);
}

// ws fragment offset (in u32): frag = ((l*3+d)*2+ks)*4+ct; 512 u32 per frag (64 lanes x 32B)
__device__ __forceinline__ size_t wfrag_off(int l, int d, int ks, int ct, int L){
    return ((((size_t)(l * 3 + d) * 2 + ks) * 4 + ct) * 64 + (size_t)L) * 8;
}

__global__ void lad_init_kernel(float* __restrict__ lad, int n){
    int i = blockIdx.x * blockDim.x + threadIdx.x;
    if (i < n) lad[i] = 0.0f;
}

// Pre-split all GEMM weights into hi/lo bf16 MFMA B-fragments, once per launch.
__global__ __launch_bounds__(64)
void w_prep_kernel(const float* __restrict__ W0, const float* __restrict__ W1,
                   const float* __restrict__ W2, unsigned* __restrict__ ws)
{
    const int b = blockIdx.x;            // 0..191 = (latent, layer)
    const int l = b / 3, d = b - 3 * l;
    const int L = threadIdx.x;
    const float* Wd = (d == 0) ? W0 + (size_t)l * 64 * IN_DIM
                    : (d == 1) ? W1 + (size_t)l * 4096
                               : W2 + (size_t)l * 4096;
    const int K = (d == 0) ? IN_DIM : 64;
    const int c  = (L & 15);
    const int kb = (L >> 4) * 8;
#pragma unroll
    for (int ks = 0; ks < 2; ++ks)
#pragma unroll
        for (int ct = 0; ct < 4; ++ct){
            const float* wr = Wd + (size_t)(ct * 16 + c) * K + ks * 32 + kb;
            float wf[8];
#pragma unroll
            for (int j = 0; j < 8; ++j) wf[j] = wr[j];
            short8 wh, wl;
            split8(wf, wh, wl);
            size_t off = wfrag_off(l, d, ks, ct, L);
            *(short8*)(ws + off)     = wh;
            *(short8*)(ws + off + 4) = wl;
        }
}

__global__ __launch_bounds__(256, 3)
void flow_mfma_kernel(const float* __restrict__ x,
                      const float* __restrict__ W0, const float* __restrict__ b0,
                      const float* __restrict__ b1, const float* __restrict__ b2,
                      const float* __restrict__ W3, const float* __restrict__ b3,
                      const unsigned* __restrict__ wsp,
                      float* __restrict__ out_res, float* __restrict__ out_lad)
{
    __shared__ unsigned h_lds[MB * 64];
    __shared__ unsigned t_lds[MB * 64];
    __shared__ float    x65s[MB];

    const int l    = blockIdx.y;
    const int row0 = blockIdx.x * MB;
    const int tid  = threadIdx.x;
    const int L    = tid & 63;
    const int wv   = tid >> 6;
    const int wr0  = wv * 16;          // this wave's private 16 rows

    // ---- stage x tile (wave-private rows; no barriers anywhere) ----
    {
        const int r  = wr0 + (L >> 2);
        const int kb = (L & 3) * 16;
        const float* xg = x + ((size_t)(row0 + r) * LATENTS + l) * IN_DIM;
#pragma unroll
        for (int j = 0; j < 16; ++j)
            *swp(h_lds, r, kb + j) = packf(xg[kb + j]);
        if ((L & 3) == 0) x65s[r] = xg[64];
    }

    const int lrow = wr0 + (L & 15);   // A-frag row for this lane
    const int lg   = L >> 4;           // k-group
    const int q0   = wr0 + lg * 4;     // D-tile row base
    const int lc   = L & 15;

    f32x4 hacc[4], tacc[4];

    auto loadw = [&](int d, int ks, int ct, short8& wh, short8& wl){
        size_t off = wfrag_off(l, d, ks, ct, L);
        wh = *(const short8*)(wsp + off);
        wl = *(const short8*)(wsp + off + 4);
    };

    // ---- layer 0: z0 = x @ W0^T + b0 (K=64 via MFMA + rank-1 col-65) ----
    {
        const float* W0l = W0 + (size_t)l * 64 * IN_DIM;
#pragma unroll
        for (int ct = 0; ct < 4; ++ct){
            float bv = b0[l * 64 + ct * 16 + lc];
            hacc[ct] = (f32x4){bv, bv, bv, bv};
        }
#pragma unroll
        for (int ks = 0; ks < 2; ++ks){
            short8 ah, al;
            read_frag(h_lds, lrow, ks * 32 + lg * 8, ah, al);
#pragma unroll
            for (int ct = 0; ct < 4; ++ct){
                short8 wh, wl;
                loadw(0, ks, ct, wh, wl);
                hacc[ct] = mfma_(ah, wh, hacc[ct]);
                hacc[ct] = mfma_(al, wh, hacc[ct]);
                hacc[ct] = mfma_(ah, wl, hacc[ct]);
            }
        }
        // rank-1 update with column 64, then activation; tangent t1 = m * W0[:,64]
        float xv[4];
#pragma unroll
        for (int i = 0; i < 4; ++i) xv[i] = x65s[q0 + i];
#pragma unroll
        for (int ct = 0; ct < 4; ++ct){
            const int c = ct * 16 + lc;
            const float w65 = W0l[(size_t)c * IN_DIM + 64];
#pragma unroll
            for (int i = 0; i < 4; ++i){
                float z = hacc[ct][i] + xv[i] * w65;
                float m = (z >= 0.0f) ? 1.0f : SLOPE;
                *swp(h_lds, q0 + i, c) = packf(m * z);
                *swp(t_lds, q0 + i, c) = packf(m * w65);
            }
        }
    }

    // ---- layers 1 and 2: h,t GEMMs (split-bf16, 3 MFMAs per product) ----
    auto dense = [&](int d, const float* __restrict__ bl){
#pragma unroll
        for (int ct = 0; ct < 4; ++ct){
            float bv = bl[ct * 16 + lc];
            hacc[ct] = (f32x4){bv, bv, bv, bv};
            tacc[ct] = (f32x4){0.f, 0.f, 0.f, 0.f};
        }
#pragma unroll
        for (int ks = 0; ks < 2; ++ks){
            short8 ah, al, th, tl;
            read_frag(h_lds, lrow, ks * 32 + lg * 8, ah, al);
            read_frag(t_lds, lrow, ks * 32 + lg * 8, th, tl);
#pragma unroll
            for (int ct = 0; ct < 4; ++ct){
                short8 wh, wl;
                loadw(d, ks, ct, wh, wl);
                hacc[ct] = mfma_(ah, wh, hacc[ct]);
                hacc[ct] = mfma_(al, wh, hacc[ct]);
                hacc[ct] = mfma_(ah, wl, hacc[ct]);
                tacc[ct] = mfma_(th, wh, tacc[ct]);
                tacc[ct] = mfma_(tl, wh, tacc[ct]);
                tacc[ct] = mfma_(th, wl, tacc[ct]);
            }
        }
#pragma unroll
        for (int ct = 0; ct < 4; ++ct){
            const int c = ct * 16 + lc;
#pragma unroll
            for (int i = 0; i < 4; ++i){
                float z = hacc[ct][i], zt = tacc[ct][i];
                float m = (z >= 0.0f) ? 1.0f : SLOPE;
                *swp(h_lds, q0 + i, c) = packf(m * z);
                *swp(t_lds, q0 + i, c) = packf(m * zt);
            }
        }
    };
    dense(1, b1 + l * 64);
    dense(2, b2 + l * 64);

    // ---- layer 3: scalar head + log|dJ| (wave-local, shfl reduce) ----
    {
        const float* w3 = W3 + l * 64;
        const int r  = wr0 + (L & 15);
        const int kq = L >> 4;
        float so = 0.0f, sd = 0.0f;
#pragma unroll
        for (int j = 0; j < 16; ++j){
            const int k = kq * 16 + j;
            const float w = w3[k];
            so += w * upackf(*swp(h_lds, r, k));
            sd += w * upackf(*swp(t_lds, r, k));
        }
        so += __shfl_xor(so, 16, 64); so += __shfl_xor(so, 32, 64);
        sd += __shfl_xor(sd, 16, 64); sd += __shfl_xor(sd, 32, 64);
        if (kq == 0){
            out_res[(size_t)(row0 + r) * LATENTS + l] = so + b3[l];
            atomicAdd(&out_lad[row0 + r], logf(fabsf(sd) + FEPS));
        }
    }
}

extern "C" void kernel_launch(void* const* d_in, const int* in_sizes, int n_in,
                              void* d_out, int out_size, void* d_ws, size_t ws_size,
                              hipStream_t stream)
{
    const float* x  = (const float*)d_in[0];
    const float* W0 = (const float*)d_in[1];
    const float* b0 = (const float*)d_in[2];
    const float* W1 = (const float*)d_in[3];
    const float* b1 = (const float*)d_in[4];
    const float* W2 = (const float*)d_in[5];
    const float* b2 = (const float*)d_in[6];
    const float* W3 = (const float*)d_in[7];
    const float* b3 = (const float*)d_in[8];

    const int B = in_sizes[0] / (LATENTS * IN_DIM);  // 8192
    float* out_res = (float*)d_out;
    float* out_lad = out_res + (size_t)B * LATENTS;
    unsigned* wsp  = (unsigned*)d_ws;  // 3 MB of pre-split weight fragments

    lad_init_kernel<<<dim3((B + 255) / 256), dim3(256), 0, stream>>>(out_lad, B);
    w_prep_kernel<<<dim3(LATENTS * 3), dim3(64), 0, stream>>>(W0, W1, W2, wsp);
    flow_mfma_kernel<<<dim3(B / MB, LATENTS), dim3(256), 0, stream>>>(
        x, W0, b0, b1, b2, W3, b3, wsp, out_res, out_lad);
}